// Round 7
// baseline (405.153 us; speedup 1.0000x reference)
//
#include <hip/hip_runtime.h>
#include <hip/hip_bf16.h>

#define HIDDEN 768
#define NB 8
#define BLK 96
#define S_LEN 8192
#define H_LEN 4096
#define M_LEN 4097
#define MP 4160           // spectrum word pitch (65*64); one (r,i) bf16 word per mode
#define BATCH 4
#define KBIG 192          // 2*BLK (interleaved r/i channels)
#define TMOD 32           // modes per MLP workgroup (32 -> 25.6 KB LDS, 6 blocks/CU)
#define APITCH 100        // act LDS row pitch in words

#define TWO_PI 6.28318530717958647692f
#define INV_SQRT_N 0.011048543456039806f   // 1/sqrt(8192)
#define C_INV 0.022097086912079612f        // 2/sqrt(8192)
#define LAM 0.01f

typedef __attribute__((ext_vector_type(8))) short short8;
typedef __attribute__((ext_vector_type(4))) float float4v;

__device__ __forceinline__ short f2bf(float f) {
    __hip_bfloat16 h = __float2bfloat16(f);
    return *reinterpret_cast<short*>(&h);
}
__device__ __forceinline__ float bf2f(unsigned short s) {
    __hip_bfloat16 h = *reinterpret_cast<__hip_bfloat16*>(&s);
    return __bfloat162float(h);
}
__device__ __forceinline__ unsigned pack2bf(float a, float b) {
    return (unsigned)(unsigned short)f2bf(a) | ((unsigned)(unsigned short)f2bf(b) << 16);
}
__device__ __forceinline__ float2 cmul(float2 a, float2 b) {
    return make_float2(a.x * b.x - a.y * b.y, a.x * b.y + a.y * b.x);
}

// ---------------------------------------------------------------------------
// P0: big-weight matrices WT[n][o'=192][kin=192], OUTPUT rows interleaved:
//   o' = 2*oc   -> real-part row of channel oc
//   o' = 2*oc+1 -> imag-part row of channel oc
// kin unchanged (even = r_d, odd = i_d). Biases bb interleaved the same way.
// ---------------------------------------------------------------------------
__global__ __launch_bounds__(256) void prep_weights(const float* __restrict__ w1,
                                                    const float* __restrict__ w2,
                                                    const float* __restrict__ b1,
                                                    const float* __restrict__ b2,
                                                    short* __restrict__ WT1,
                                                    short* __restrict__ WT2,
                                                    float* __restrict__ bb1,
                                                    float* __restrict__ bb2) {
    int idx = blockIdx.x * 256 + threadIdx.x;
    if (idx < NB * KBIG * KBIG) {
        int n = idx / (KBIG * KBIG);
        int r = idx % (KBIG * KBIG);
        int op = r / KBIG;         // interleaved output row
        int kin = r % KBIG;
        int oc = op >> 1;
        int oim = op & 1;
        int d = kin >> 1;
        int im = kin & 1;
        {
            float w0 = w1[((size_t)(0 * NB + n) * BLK + d) * BLK + oc];
            float wi = w1[((size_t)(1 * NB + n) * BLK + d) * BLK + oc];
            float v = oim ? (im ? w0 : wi) : (im ? -wi : w0);
            WT1[idx] = f2bf(v);
        }
        {
            float w0 = w2[((size_t)(0 * NB + n) * BLK + d) * BLK + oc];
            float wi = w2[((size_t)(1 * NB + n) * BLK + d) * BLK + oc];
            float v = oim ? (im ? w0 : wi) : (im ? -wi : w0);
            WT2[idx] = f2bf(v);
        }
    }
    if (idx < NB * KBIG) {
        int n = idx / KBIG, op = idx % KBIG;
        int oc = op >> 1, oim = op & 1;
        bb1[idx] = oim ? b1[(1 * NB + n) * BLK + oc] : b1[(0 * NB + n) * BLK + oc];
        bb2[idx] = oim ? b2[(1 * NB + n) * BLK + oc] : b2[(0 * NB + n) * BLK + oc];
    }
}

// ---------------------------------------------------------------------------
// P1: twiddle tables.
// ---------------------------------------------------------------------------
__global__ __launch_bounds__(256) void init_twiddles(float2* __restrict__ tw4k,
                                                     float2* __restrict__ tw8k) {
    int i = blockIdx.x * 256 + threadIdx.x;
    if (i < 4096) {
        float ang = -TWO_PI * (float)i * (1.0f / 4096.0f);
        tw4k[i] = make_float2(cosf(ang), sinf(ang));
    }
    if (i <= 4096) {
        float ang = -TWO_PI * (float)i * (1.0f / 8192.0f);
        tw8k[i] = make_float2(cosf(ang), sinf(ang));
    }
}

// ---------------------------------------------------------------------------
// K0: x [B,S,C] f32 -> xT [B*C, S] bf16. 64x64 tiles, float4 reads (16B/lane),
// short4 writes (8B/lane). LDS pitch 66 floats: scatter 4-way, float2 gather
// at structural-min banking, 8B-aligned rows.
// ---------------------------------------------------------------------------
__global__ __launch_bounds__(256) void transpose_in(const float* __restrict__ x,
                                                    __hip_bfloat16* __restrict__ xT) {
    __shared__ float t[64][66];
    const int cb = blockIdx.x, sb = blockIdx.y, b = blockIdx.z;
    const int tid = threadIdx.x;
    {
        const int cq = tid & 15, sr = tid >> 4;
        const float* xp = x + ((size_t)(b * S_LEN + sb * 64 + sr)) * HIDDEN + cb * 64 + cq * 4;
        #pragma unroll
        for (int i = 0; i < 4; i++) {
            float4 v = *(const float4*)(xp + (size_t)16 * i * HIDDEN);
            int s = sr + 16 * i;
            t[cq * 4 + 0][s] = v.x;
            t[cq * 4 + 1][s] = v.y;
            t[cq * 4 + 2][s] = v.z;
            t[cq * 4 + 3][s] = v.w;
        }
    }
    __syncthreads();
    {
        const int s4 = tid & 15, cr = tid >> 4;
        #pragma unroll
        for (int i = 0; i < 4; i++) {
            int c = cr + 16 * i;
            float2 a = *(const float2*)&t[c][s4 * 4];
            float2 bv = *(const float2*)&t[c][s4 * 4 + 2];
            short4 o;
            o.x = f2bf(a.x); o.y = f2bf(a.y); o.z = f2bf(bv.x); o.w = f2bf(bv.y);
            *(short4*)(xT + ((size_t)(b * HIDDEN + cb * 64 + c)) * S_LEN + sb * 64 + s4 * 4) = o;
        }
    }
}

// ---------------------------------------------------------------------------
// In-place 16-point DFT (two radix-4 stages, compile-time W16 twiddles).
// ---------------------------------------------------------------------------
template<bool INV>
__device__ __forceinline__ void dft16(float2* v) {
    const float s3 = INV ? -1.f : 1.f;
    constexpr float C1 = 0.92387953251128674f;  // cos(pi/8)
    constexpr float S1 = 0.38268343236508977f;  // sin(pi/8)
    constexpr float R2 = 0.70710678118654752f;  // sqrt(2)/2
    float2 a[16];
    #pragma unroll
    for (int na = 0; na < 4; na++) {            // radix-4 over n_b (stride 4)
        float2 x0 = v[na], x1 = v[na + 4], x2 = v[na + 8], x3 = v[na + 12];
        float t0x = x0.x + x2.x, t0y = x0.y + x2.y;
        float t1x = x0.x - x2.x, t1y = x0.y - x2.y;
        float t2x = x1.x + x3.x, t2y = x1.y + x3.y;
        float t3x = x1.x - x3.x, t3y = x1.y - x3.y;
        a[na]      = make_float2(t0x + t2x, t0y + t2y);
        a[na + 8]  = make_float2(t0x - t2x, t0y - t2y);
        a[na + 4]  = make_float2(t1x + s3 * t3y, t1y - s3 * t3x);
        a[na + 12] = make_float2(t1x - s3 * t3y, t1y + s3 * t3x);
    }
    auto tw = [s3](float2 z, float ce, float se) {
        return make_float2(z.x * ce + s3 * z.y * se, z.y * ce - s3 * z.x * se);
    };
    a[5]  = tw(a[5],  C1,  S1);   // e=1
    a[6]  = tw(a[6],  R2,  R2);   // e=2
    a[7]  = tw(a[7],  S1,  C1);   // e=3
    a[9]  = tw(a[9],  R2,  R2);   // e=2
    a[10] = tw(a[10], 0.f, 1.f);  // e=4
    a[11] = tw(a[11], -R2, R2);   // e=6
    a[13] = tw(a[13], S1,  C1);   // e=3
    a[14] = tw(a[14], -R2, R2);   // e=6
    a[15] = tw(a[15], -C1, -S1);  // e=9
    #pragma unroll
    for (int kb = 0; kb < 4; kb++) {            // radix-4 over n_a (contiguous)
        float2 x0 = a[4 * kb], x1 = a[4 * kb + 1], x2 = a[4 * kb + 2], x3 = a[4 * kb + 3];
        float t0x = x0.x + x2.x, t0y = x0.y + x2.y;
        float t1x = x0.x - x2.x, t1y = x0.y - x2.y;
        float t2x = x1.x + x3.x, t2y = x1.y + x3.y;
        float t3x = x1.x - x3.x, t3y = x1.y - x3.y;
        v[kb]      = make_float2(t0x + t2x, t0y + t2y);
        v[kb + 8]  = make_float2(t0x - t2x, t0y - t2y);
        v[kb + 4]  = make_float2(t1x + s3 * t3y, t1y - s3 * t3x);
        v[kb + 12] = make_float2(t1x - s3 * t3y, t1y + s3 * t3x);
    }
}

// ---------------------------------------------------------------------------
// 4096-point FFT as 16^3: three in-register DFT-16s, two LDS transposes.
// ---------------------------------------------------------------------------
template<bool INV>
__device__ __forceinline__ void fft3pass(float2* v, float2* arr,
                                         const float2* __restrict__ tw4k, int t) {
    const float sg = INV ? -1.f : 1.f;
    const int n0 = t & 15;
    const int hi = t >> 4;

    // stage 1: DFT16 over j, twiddle W4096^{t*p}, scatter (row n0+16p, col hi)
    dft16<INV>(v);
    arr[n0 * 17 + hi] = v[0];
    #pragma unroll
    for (int p = 1; p < 16; p++) {
        float2 w = tw4k[(t * p) & 4095];
        arr[(n0 + 16 * p) * 17 + hi] = cmul(v[p], make_float2(w.x, sg * w.y));
    }
    __syncthreads();

    // stage 2: row read, DFT16 over n1=hi, twiddle W256^{n0*q}, scatter
    #pragma unroll
    for (int n1 = 0; n1 < 16; n1++) v[n1] = arr[t * 17 + n1];
    __syncthreads();
    dft16<INV>(v);
    arr[hi * 17 + n0] = v[0];
    #pragma unroll
    for (int q = 1; q < 16; q++) {
        float2 w = tw4k[(16 * n0 * q) & 4095];
        arr[(hi + 16 * q) * 17 + n0] = cmul(v[q], make_float2(w.x, sg * w.y));
    }
    __syncthreads();

    // stage 3: row read, DFT16 over n0 -> X[t + 256*k0]
    #pragma unroll
    for (int i = 0; i < 16; i++) v[i] = arr[t * 17 + i];
    dft16<INV>(v);
}

// ---------------------------------------------------------------------------
// K1: forward rfft per (b,c) -> interleaved (r,i) bf16 words Xc[row][m]
// ---------------------------------------------------------------------------
__global__ __launch_bounds__(256, 4) void fft_fwd(const __hip_bfloat16* __restrict__ xT,
                                                  unsigned int* __restrict__ Xc,
                                                  const float2* __restrict__ tw4k,
                                                  const float2* __restrict__ tw8k) {
    __shared__ __align__(16) float2 arr[256 * 17];   // 34816 B; reused flat [4096]
    const int wg = blockIdx.x;         // b*HIDDEN + c
    const int t = threadIdx.x;
    const __hip_bfloat162* xrow = (const __hip_bfloat162*)(xT + (size_t)wg * S_LEN);

    float2 v[16];
    #pragma unroll
    for (int j = 0; j < 16; j++) {     // coalesced: lane-consecutive 4B
        __hip_bfloat162 pz = xrow[t + 256 * j];
        v[j] = make_float2(__bfloat162float(pz.x), __bfloat162float(pz.y));
    }

    fft3pass<false>(v, arr, tw4k, t);

    // park natural-order spectrum in LDS for the rfft untangle
    __syncthreads();
    #pragma unroll
    for (int k0 = 0; k0 < 16; k0++) arr[t + 256 * k0] = v[k0];
    __syncthreads();

    unsigned int* Xrow = Xc + (size_t)wg * MP;
    for (int m = t; m <= H_LEN; m += 256) {
        int ia = m & (H_LEN - 1);
        int ib = (H_LEN - m) & (H_LEN - 1);
        float2 za = arr[ia];
        float2 zb = arr[ib];
        float er = 0.5f * (za.x + zb.x), ei = 0.5f * (za.y - zb.y);
        float dr = za.x - zb.x, di = za.y + zb.y;
        float or_ = 0.5f * di, oi = -0.5f * dr;
        float2 tt = tw8k[m];                       // exp(-2*pi*i*m/8192)
        float xrv = (er + tt.x * or_ - tt.y * oi) * INV_SQRT_N;
        float xiv = (ei + tt.x * oi + tt.y * or_) * INV_SQRT_N;
        unsigned wd = (unsigned short)f2bf(xrv) | ((unsigned)(unsigned short)f2bf(xiv) << 16);
        Xrow[m] = wd;
    }
}

// ---------------------------------------------------------------------------
// K2: MFMA block-diagonal complex MLP, in place over Xc.
// act LDS layout: [mode m][kword d] (pitch APITCH words). TMOD=32 -> 25.6 KB
// total LDS -> 6 blocks/CU for latency hiding. Staging: lane owns mode
// (tid&31) and 12-word d-group -> coalesced global dwords + b128 LDS ops.
// ---------------------------------------------------------------------------
__global__ __launch_bounds__(256, 3) void mlp_mfma(const short* __restrict__ WT1,
                                                   const short* __restrict__ WT2,
                                                   const float* __restrict__ bb1,
                                                   const float* __restrict__ bb2,
                                                   unsigned int* __restrict__ Xc) {
    __shared__ __align__(16) unsigned int actA[TMOD * APITCH];  // 12.8 KB
    __shared__ __align__(16) unsigned int actB[TMOD * APITCH];  // 12.8 KB
    const int tid = threadIdx.x;
    const int chunk = blockIdx.x;          // 0..128
    const int n = blockIdx.y;
    const int b = blockIdx.z;
    const int m0 = chunk * TMOD;
    unsigned int* __restrict__ Xrow0 =
        Xc + ((size_t)b * HIDDEN + (size_t)n * BLK) * MP + m0;

    const int w = tid >> 6;                // wave 0..3
    const int l15 = tid & 15;
    const int q = (tid >> 4) & 3;
    const int outw = w * 48;
    const int mstg = tid & 31;             // staging: mode owned by this lane
    const int g8 = tid >> 5;               // staging: 12-word d-group 0..7

    // ---- stage: 3 passes of 4 coalesced global dwords -> 1 b128 LDS write
    #pragma unroll
    for (int dp = 0; dp < 3; dp++) {
        int d0 = g8 * 12 + dp * 4;
        uint4 vv;
        vv.x = Xrow0[(size_t)(d0 + 0) * MP + mstg];
        vv.y = Xrow0[(size_t)(d0 + 1) * MP + mstg];
        vv.z = Xrow0[(size_t)(d0 + 2) * MP + mstg];
        vv.w = Xrow0[(size_t)(d0 + 3) * MP + mstg];
        *(uint4*)&actA[mstg * APITCH + d0] = vv;
    }

    // ---- layer-1 weight fragments (latency overlaps staging + barrier)
    short8 wf[3][6];
    for (int nl = 0; nl < 3; nl++)
        for (int ks = 0; ks < 6; ks++)
            wf[nl][ks] = *(const short8*)(WT1 + ((size_t)n * KBIG + outw + nl * 16 + l15) * KBIG + ks * 32 + q * 8);

    __syncthreads();

    // ---- layer 1 ----
    for (int mt = 0; mt < 2; mt++) {
        float4v acc[3];
        for (int nl = 0; nl < 3; nl++)
            acc[nl] = *(const float4v*)(bb1 + n * KBIG + outw + nl * 16 + q * 4);
        #pragma unroll
        for (int ks = 0; ks < 6; ks++) {
            short8 bf = *(const short8*)(&actA[(mt * 16 + l15) * APITCH + ks * 16 + q * 4]);
            acc[0] = __builtin_amdgcn_mfma_f32_16x16x32_bf16(wf[0][ks], bf, acc[0], 0, 0, 0);
            acc[1] = __builtin_amdgcn_mfma_f32_16x16x32_bf16(wf[1][ks], bf, acc[1], 0, 0, 0);
            acc[2] = __builtin_amdgcn_mfma_f32_16x16x32_bf16(wf[2][ks], bf, acc[2], 0, 0, 0);
        }
        #pragma unroll
        for (int nl = 0; nl < 3; nl++) {
            uint2 st;
            st.x = pack2bf(fmaxf(acc[nl][0], 0.f), fmaxf(acc[nl][1], 0.f));
            st.y = pack2bf(fmaxf(acc[nl][2], 0.f), fmaxf(acc[nl][3], 0.f));
            *(uint2*)&actB[(mt * 16 + l15) * APITCH + outw / 2 + nl * 8 + q * 2] = st;
        }
    }

    // ---- layer-2 weight fragments (latency overlaps barrier)
    short8 wf2[3][6];
    for (int nl = 0; nl < 3; nl++)
        for (int ks = 0; ks < 6; ks++)
            wf2[nl][ks] = *(const short8*)(WT2 + ((size_t)n * KBIG + outw + nl * 16 + l15) * KBIG + ks * 32 + q * 8);

    __syncthreads();

    // ---- layer 2 ----
    for (int mt = 0; mt < 2; mt++) {
        float4v acc[3];
        for (int nl = 0; nl < 3; nl++)
            acc[nl] = *(const float4v*)(bb2 + n * KBIG + outw + nl * 16 + q * 4);
        #pragma unroll
        for (int ks = 0; ks < 6; ks++) {
            short8 bf = *(const short8*)(&actB[(mt * 16 + l15) * APITCH + ks * 16 + q * 4]);
            acc[0] = __builtin_amdgcn_mfma_f32_16x16x32_bf16(wf2[0][ks], bf, acc[0], 0, 0, 0);
            acc[1] = __builtin_amdgcn_mfma_f32_16x16x32_bf16(wf2[1][ks], bf, acc[1], 0, 0, 0);
            acc[2] = __builtin_amdgcn_mfma_f32_16x16x32_bf16(wf2[2][ks], bf, acc[2], 0, 0, 0);
        }
        #pragma unroll
        for (int nl = 0; nl < 3; nl++) {
            float v0 = acc[nl][0], v1 = acc[nl][1], v2 = acc[nl][2], v3 = acc[nl][3];
            v0 = copysignf(fmaxf(fabsf(v0) - LAM, 0.f), v0);
            v1 = copysignf(fmaxf(fabsf(v1) - LAM, 0.f), v1);
            v2 = copysignf(fmaxf(fabsf(v2) - LAM, 0.f), v2);
            v3 = copysignf(fmaxf(fabsf(v3) - LAM, 0.f), v3);
            uint2 st;
            st.x = pack2bf(v0, v1);
            st.y = pack2bf(v2, v3);
            *(uint2*)&actA[(mt * 16 + l15) * APITCH + outw / 2 + nl * 8 + q * 2] = st;
        }
    }
    __syncthreads();

    // ---- write back: words already in global (r,i) format; b128 + coalesced
    #pragma unroll
    for (int dp = 0; dp < 3; dp++) {
        int d0 = g8 * 12 + dp * 4;
        uint4 vv = *(const uint4*)&actA[mstg * APITCH + d0];
        Xrow0[(size_t)(d0 + 0) * MP + mstg] = vv.x;
        Xrow0[(size_t)(d0 + 1) * MP + mstg] = vv.y;
        Xrow0[(size_t)(d0 + 2) * MP + mstg] = vv.z;
        Xrow0[(size_t)(d0 + 3) * MP + mstg] = vv.w;
    }
}

// ---------------------------------------------------------------------------
// K3: inverse rfft per (b,c): Xc -> yT [B*C, S] bf16
// ---------------------------------------------------------------------------
__global__ __launch_bounds__(256, 4) void fft_inv(const unsigned int* __restrict__ Xc,
                                                  __hip_bfloat16* __restrict__ yT,
                                                  const float2* __restrict__ tw4k,
                                                  const float2* __restrict__ tw8k) {
    __shared__ __align__(16) float2 arr[256 * 17];
    const int wg = blockIdx.x;
    const int t = threadIdx.x;
    const unsigned int* Xrow = Xc + (size_t)wg * MP;

    float2 v[16];
    #pragma unroll
    for (int j = 0; j < 16; j++) {
        int m = t + 256 * j;                       // [0,4095], coalesced
        unsigned va = Xrow[m];
        unsigned vb = Xrow[H_LEN - m];             // descending, coalesced
        float arv = bf2f((unsigned short)(va & 0xFFFF));
        float aiv = bf2f((unsigned short)(va >> 16));
        float brv = bf2f((unsigned short)(vb & 0xFFFF));
        float biv = bf2f((unsigned short)(vb >> 16));
        if (m == 0) { aiv = 0.f; biv = 0.f; }      // numpy irfft drops Im(Y0), Im(YH)
        float er = 0.5f * (arv + brv), ei = 0.5f * (aiv - biv);
        float dr = arv - brv, di = aiv + biv;
        float2 tt = tw8k[m];                       // need exp(+2*pi*i*m/8192)
        float wcs = tt.x, wsn = -tt.y;
        float or_ = 0.5f * (wcs * dr - wsn * di);
        float oi = 0.5f * (wcs * di + wsn * dr);
        v[j] = make_float2(er - oi, ei + or_);
    }

    fft3pass<true>(v, arr, tw4k, t);

    __hip_bfloat162* orow = (__hip_bfloat162*)(yT + (size_t)wg * S_LEN);
    #pragma unroll
    for (int k0 = 0; k0 < 16; k0++) {              // coalesced 4B stores
        __hip_bfloat162 w;
        w.x = __float2bfloat16(C_INV * v[k0].x);
        w.y = __float2bfloat16(C_INV * v[k0].y);
        orow[t + 256 * k0] = w;
    }
}

// ---------------------------------------------------------------------------
// K4: out[b,s,c] = x[b,s,c] + yT[b*C+c, s]. 64x64 tiles, short4 yT reads,
// float4 x read + float4 out write.
// ---------------------------------------------------------------------------
__global__ __launch_bounds__(256) void add_out(const __hip_bfloat16* __restrict__ yT,
                                               const float* __restrict__ x,
                                               float* __restrict__ out) {
    __shared__ float t[64][66];
    const int cb = blockIdx.x, sb = blockIdx.y, b = blockIdx.z;
    const int tid = threadIdx.x;
    {
        const int s4 = tid & 15, cr = tid >> 4;
        #pragma unroll
        for (int i = 0; i < 4; i++) {
            int c = cr + 16 * i;
            short4 v = *(const short4*)(yT + ((size_t)(b * HIDDEN + cb * 64 + c)) * S_LEN + sb * 64 + s4 * 4);
            t[s4 * 4 + 0][c] = bf2f((unsigned short)v.x);
            t[s4 * 4 + 1][c] = bf2f((unsigned short)v.y);
            t[s4 * 4 + 2][c] = bf2f((unsigned short)v.z);
            t[s4 * 4 + 3][c] = bf2f((unsigned short)v.w);
        }
    }
    __syncthreads();
    {
        const int cq = tid & 15, sr = tid >> 4;
        #pragma unroll
        for (int i = 0; i < 4; i++) {
            int s = sr + 16 * i;
            const size_t off = ((size_t)(b * S_LEN + sb * 64 + s)) * HIDDEN + cb * 64 + cq * 4;
            float4 xv = *(const float4*)(x + off);
            float2 a = *(const float2*)&t[s][cq * 4];
            float2 bv = *(const float2*)&t[s][cq * 4 + 2];
            float4 ov;
            ov.x = xv.x + a.x; ov.y = xv.y + a.y; ov.z = xv.z + bv.x; ov.w = xv.w + bv.y;
            *(float4*)(out + off) = ov;
        }
    }
}

// ---------------------------------------------------------------------------
extern "C" void kernel_launch(void* const* d_in, const int* in_sizes, int n_in,
                              void* d_out, int out_size, void* d_ws, size_t ws_size,
                              hipStream_t stream) {
    const float* x  = (const float*)d_in[0];
    const float* w1 = (const float*)d_in[1];
    const float* b1 = (const float*)d_in[2];
    const float* w2 = (const float*)d_in[3];
    const float* b2 = (const float*)d_in[4];
    float* out = (float*)d_out;

    char* p = (char*)d_ws;
    __hip_bfloat16* xT = (__hip_bfloat16*)p;           p += (size_t)BATCH * HIDDEN * S_LEN * 2;
    unsigned int*   Xc = (unsigned int*)p;             p += (size_t)BATCH * HIDDEN * MP * 4;
    short* WT1 = (short*)p;                            p += (size_t)NB * KBIG * KBIG * 2;
    short* WT2 = (short*)p;                            p += (size_t)NB * KBIG * KBIG * 2;
    float* bb1 = (float*)p;                            p += (size_t)NB * KBIG * 4;
    float* bb2 = (float*)p;                            p += (size_t)NB * KBIG * 4;
    float2* tw4k = (float2*)p;                         p += (size_t)4096 * sizeof(float2);
    float2* tw8k = (float2*)p;                         p += (size_t)4100 * sizeof(float2);

    prep_weights<<<(NB * KBIG * KBIG + 255) / 256, 256, 0, stream>>>(
        w1, w2, b1, b2, WT1, WT2, bb1, bb2);

    init_twiddles<<<17, 256, 0, stream>>>(tw4k, tw8k);

    transpose_in<<<dim3(HIDDEN / 64, S_LEN / 64, BATCH), 256, 0, stream>>>(x, xT);

    fft_fwd<<<BATCH * HIDDEN, 256, 0, stream>>>(xT, Xc, tw4k, tw8k);

    mlp_mfma<<<dim3(129, NB, BATCH), 256, 0, stream>>>(WT1, WT2, bb1, bb2, Xc);

    fft_inv<<<BATCH * HIDDEN, 256, 0, stream>>>(Xc, xT /* as yT */, tw4k, tw8k);

    add_out<<<dim3(HIDDEN / 64, S_LEN / 64, BATCH), 256, 0, stream>>>(xT, x, out);
}

// Round 8
// 350.212 us; speedup vs baseline: 1.1569x; 1.1569x over previous
//
#include <hip/hip_runtime.h>
#include <hip/hip_bf16.h>

#define HIDDEN 768
#define NB 8
#define BLK 96
#define S_LEN 8192
#define H_LEN 4096
#define M_LEN 4097
#define MP 4160           // spectrum word pitch (65*64); one (r,i) bf16 word per mode
#define BATCH 4
#define KBIG 192          // 2*BLK (interleaved r/i channels)
#define TMOD 64           // modes per MLP workgroup
#define APITCH 100        // act LDS row pitch in words

#define TWO_PI 6.28318530717958647692f
#define INV_SQRT_N 0.011048543456039806f   // 1/sqrt(8192)
#define C_INV 0.022097086912079612f        // 2/sqrt(8192)
#define LAM 0.01f

typedef __attribute__((ext_vector_type(8))) short short8;
typedef __attribute__((ext_vector_type(4))) float float4v;

__device__ __forceinline__ short f2bf(float f) {
    __hip_bfloat16 h = __float2bfloat16(f);
    return *reinterpret_cast<short*>(&h);
}
__device__ __forceinline__ float bf2f(unsigned short s) {
    __hip_bfloat16 h = *reinterpret_cast<__hip_bfloat16*>(&s);
    return __bfloat162float(h);
}
__device__ __forceinline__ unsigned pack2bf(float a, float b) {
    return (unsigned)(unsigned short)f2bf(a) | ((unsigned)(unsigned short)f2bf(b) << 16);
}
__device__ __forceinline__ float2 cmul(float2 a, float2 b) {
    return make_float2(a.x * b.x - a.y * b.y, a.x * b.y + a.y * b.x);
}

// ---------------------------------------------------------------------------
// P0: big-weight matrices WT[n][o'=192][kin=192], OUTPUT rows interleaved:
//   o' = 2*oc   -> real-part row of channel oc
//   o' = 2*oc+1 -> imag-part row of channel oc
// kin unchanged (even = r_d, odd = i_d). Biases bb interleaved the same way.
// ---------------------------------------------------------------------------
__global__ __launch_bounds__(256) void prep_weights(const float* __restrict__ w1,
                                                    const float* __restrict__ w2,
                                                    const float* __restrict__ b1,
                                                    const float* __restrict__ b2,
                                                    short* __restrict__ WT1,
                                                    short* __restrict__ WT2,
                                                    float* __restrict__ bb1,
                                                    float* __restrict__ bb2) {
    int idx = blockIdx.x * 256 + threadIdx.x;
    if (idx < NB * KBIG * KBIG) {
        int n = idx / (KBIG * KBIG);
        int r = idx % (KBIG * KBIG);
        int op = r / KBIG;         // interleaved output row
        int kin = r % KBIG;
        int oc = op >> 1;
        int oim = op & 1;
        int d = kin >> 1;
        int im = kin & 1;
        {
            float w0 = w1[((size_t)(0 * NB + n) * BLK + d) * BLK + oc];
            float wi = w1[((size_t)(1 * NB + n) * BLK + d) * BLK + oc];
            float v = oim ? (im ? w0 : wi) : (im ? -wi : w0);
            WT1[idx] = f2bf(v);
        }
        {
            float w0 = w2[((size_t)(0 * NB + n) * BLK + d) * BLK + oc];
            float wi = w2[((size_t)(1 * NB + n) * BLK + d) * BLK + oc];
            float v = oim ? (im ? w0 : wi) : (im ? -wi : w0);
            WT2[idx] = f2bf(v);
        }
    }
    if (idx < NB * KBIG) {
        int n = idx / KBIG, op = idx % KBIG;
        int oc = op >> 1, oim = op & 1;
        bb1[idx] = oim ? b1[(1 * NB + n) * BLK + oc] : b1[(0 * NB + n) * BLK + oc];
        bb2[idx] = oim ? b2[(1 * NB + n) * BLK + oc] : b2[(0 * NB + n) * BLK + oc];
    }
}

// ---------------------------------------------------------------------------
// P1: twiddle tables.
// ---------------------------------------------------------------------------
__global__ __launch_bounds__(256) void init_twiddles(float2* __restrict__ tw4k,
                                                     float2* __restrict__ tw8k) {
    int i = blockIdx.x * 256 + threadIdx.x;
    if (i < 4096) {
        float ang = -TWO_PI * (float)i * (1.0f / 4096.0f);
        tw4k[i] = make_float2(cosf(ang), sinf(ang));
    }
    if (i <= 4096) {
        float ang = -TWO_PI * (float)i * (1.0f / 8192.0f);
        tw8k[i] = make_float2(cosf(ang), sinf(ang));
    }
}

// ---------------------------------------------------------------------------
// K0: x [B,S,C] f32 -> xT [B*C, S] bf16. 64x64 tiles, float4 reads (16B/lane),
// short4 writes (8B/lane).
// ---------------------------------------------------------------------------
__global__ __launch_bounds__(256) void transpose_in(const float* __restrict__ x,
                                                    __hip_bfloat16* __restrict__ xT) {
    __shared__ float t[64][66];
    const int cb = blockIdx.x, sb = blockIdx.y, b = blockIdx.z;
    const int tid = threadIdx.x;
    {
        const int cq = tid & 15, sr = tid >> 4;
        const float* xp = x + ((size_t)(b * S_LEN + sb * 64 + sr)) * HIDDEN + cb * 64 + cq * 4;
        #pragma unroll
        for (int i = 0; i < 4; i++) {
            float4 v = *(const float4*)(xp + (size_t)16 * i * HIDDEN);
            int s = sr + 16 * i;
            t[cq * 4 + 0][s] = v.x;
            t[cq * 4 + 1][s] = v.y;
            t[cq * 4 + 2][s] = v.z;
            t[cq * 4 + 3][s] = v.w;
        }
    }
    __syncthreads();
    {
        const int s4 = tid & 15, cr = tid >> 4;
        #pragma unroll
        for (int i = 0; i < 4; i++) {
            int c = cr + 16 * i;
            float2 a = *(const float2*)&t[c][s4 * 4];
            float2 bv = *(const float2*)&t[c][s4 * 4 + 2];
            short4 o;
            o.x = f2bf(a.x); o.y = f2bf(a.y); o.z = f2bf(bv.x); o.w = f2bf(bv.y);
            *(short4*)(xT + ((size_t)(b * HIDDEN + cb * 64 + c)) * S_LEN + sb * 64 + s4 * 4) = o;
        }
    }
}

// ---------------------------------------------------------------------------
// In-place 16-point DFT (two radix-4 stages, compile-time W16 twiddles).
// ---------------------------------------------------------------------------
template<bool INV>
__device__ __forceinline__ void dft16(float2* v) {
    const float s3 = INV ? -1.f : 1.f;
    constexpr float C1 = 0.92387953251128674f;  // cos(pi/8)
    constexpr float S1 = 0.38268343236508977f;  // sin(pi/8)
    constexpr float R2 = 0.70710678118654752f;  // sqrt(2)/2
    float2 a[16];
    #pragma unroll
    for (int na = 0; na < 4; na++) {            // radix-4 over n_b (stride 4)
        float2 x0 = v[na], x1 = v[na + 4], x2 = v[na + 8], x3 = v[na + 12];
        float t0x = x0.x + x2.x, t0y = x0.y + x2.y;
        float t1x = x0.x - x2.x, t1y = x0.y - x2.y;
        float t2x = x1.x + x3.x, t2y = x1.y + x3.y;
        float t3x = x1.x - x3.x, t3y = x1.y - x3.y;
        a[na]      = make_float2(t0x + t2x, t0y + t2y);
        a[na + 8]  = make_float2(t0x - t2x, t0y - t2y);
        a[na + 4]  = make_float2(t1x + s3 * t3y, t1y - s3 * t3x);
        a[na + 12] = make_float2(t1x - s3 * t3y, t1y + s3 * t3x);
    }
    auto tw = [s3](float2 z, float ce, float se) {
        return make_float2(z.x * ce + s3 * z.y * se, z.y * ce - s3 * z.x * se);
    };
    a[5]  = tw(a[5],  C1,  S1);   // e=1
    a[6]  = tw(a[6],  R2,  R2);   // e=2
    a[7]  = tw(a[7],  S1,  C1);   // e=3
    a[9]  = tw(a[9],  R2,  R2);   // e=2
    a[10] = tw(a[10], 0.f, 1.f);  // e=4
    a[11] = tw(a[11], -R2, R2);   // e=6
    a[13] = tw(a[13], S1,  C1);   // e=3
    a[14] = tw(a[14], -R2, R2);   // e=6
    a[15] = tw(a[15], -C1, -S1);  // e=9
    #pragma unroll
    for (int kb = 0; kb < 4; kb++) {            // radix-4 over n_a (contiguous)
        float2 x0 = a[4 * kb], x1 = a[4 * kb + 1], x2 = a[4 * kb + 2], x3 = a[4 * kb + 3];
        float t0x = x0.x + x2.x, t0y = x0.y + x2.y;
        float t1x = x0.x - x2.x, t1y = x0.y - x2.y;
        float t2x = x1.x + x3.x, t2y = x1.y + x3.y;
        float t3x = x1.x - x3.x, t3y = x1.y - x3.y;
        v[kb]      = make_float2(t0x + t2x, t0y + t2y);
        v[kb + 8]  = make_float2(t0x - t2x, t0y - t2y);
        v[kb + 4]  = make_float2(t1x + s3 * t3y, t1y - s3 * t3x);
        v[kb + 12] = make_float2(t1x - s3 * t3y, t1y + s3 * t3x);
    }
}

// ---------------------------------------------------------------------------
// 4096-point FFT as 16^3: three in-register DFT-16s, two LDS transposes.
// Twiddles: only 2 table loads per thread (both coalesced/broadcast);
// higher powers generated in-register by a running complex product
// (p <= 15, error ~1e-6, far below bf16 rounding). This removes ~30
// wide-scatter VMEM gathers per thread that stalled the wave.
// ---------------------------------------------------------------------------
template<bool INV>
__device__ __forceinline__ void fft3pass(float2* v, float2* arr,
                                         const float2* __restrict__ tw4k, int t) {
    const int n0 = t & 15;
    const int hi = t >> 4;

    // stage 1: DFT16 over j, twiddle W4096^{t*p}, scatter (row n0+16p, col hi)
    float2 w1 = tw4k[t];                  // exp(-2pi i t/4096), lane-coalesced
    if (INV) w1.y = -w1.y;
    dft16<INV>(v);
    arr[n0 * 17 + hi] = v[0];
    {
        float2 wp = w1;
        #pragma unroll
        for (int p = 1; p < 16; p++) {
            arr[(n0 + 16 * p) * 17 + hi] = cmul(v[p], wp);
            wp = cmul(wp, w1);
        }
    }
    __syncthreads();

    // stage 2: row read, DFT16 over n1=hi, twiddle W256^{n0*q}, scatter
    #pragma unroll
    for (int n1 = 0; n1 < 16; n1++) v[n1] = arr[t * 17 + n1];
    __syncthreads();
    dft16<INV>(v);
    float2 w2 = tw4k[16 * n0];            // exp(-2pi i n0/256), 16-way bcast
    if (INV) w2.y = -w2.y;
    arr[hi * 17 + n0] = v[0];
    {
        float2 wp = w2;
        #pragma unroll
        for (int q = 1; q < 16; q++) {
            arr[(hi + 16 * q) * 17 + n0] = cmul(v[q], wp);
            wp = cmul(wp, w2);
        }
    }
    __syncthreads();

    // stage 3: row read, DFT16 over n0 -> X[t + 256*k0]
    #pragma unroll
    for (int i = 0; i < 16; i++) v[i] = arr[t * 17 + i];
    dft16<INV>(v);
}

// ---------------------------------------------------------------------------
// K1: forward rfft per (b,c) -> interleaved (r,i) bf16 words Xc[row][m]
// ---------------------------------------------------------------------------
__global__ __launch_bounds__(256, 4) void fft_fwd(const __hip_bfloat16* __restrict__ xT,
                                                  unsigned int* __restrict__ Xc,
                                                  const float2* __restrict__ tw4k,
                                                  const float2* __restrict__ tw8k) {
    __shared__ __align__(16) float2 arr[256 * 17];   // 34816 B; reused flat [4096]
    const int wg = blockIdx.x;         // b*HIDDEN + c
    const int t = threadIdx.x;
    const __hip_bfloat162* xrow = (const __hip_bfloat162*)(xT + (size_t)wg * S_LEN);

    float2 v[16];
    #pragma unroll
    for (int j = 0; j < 16; j++) {     // coalesced: lane-consecutive 4B
        __hip_bfloat162 pz = xrow[t + 256 * j];
        v[j] = make_float2(__bfloat162float(pz.x), __bfloat162float(pz.y));
    }

    fft3pass<false>(v, arr, tw4k, t);

    // park natural-order spectrum in LDS for the rfft untangle
    __syncthreads();
    #pragma unroll
    for (int k0 = 0; k0 < 16; k0++) arr[t + 256 * k0] = v[k0];
    __syncthreads();

    unsigned int* Xrow = Xc + (size_t)wg * MP;
    for (int m = t; m <= H_LEN; m += 256) {
        int ia = m & (H_LEN - 1);
        int ib = (H_LEN - m) & (H_LEN - 1);
        float2 za = arr[ia];
        float2 zb = arr[ib];
        float er = 0.5f * (za.x + zb.x), ei = 0.5f * (za.y - zb.y);
        float dr = za.x - zb.x, di = za.y + zb.y;
        float or_ = 0.5f * di, oi = -0.5f * dr;
        float2 tt = tw8k[m];                       // exp(-2*pi*i*m/8192)
        float xrv = (er + tt.x * or_ - tt.y * oi) * INV_SQRT_N;
        float xiv = (ei + tt.x * oi + tt.y * or_) * INV_SQRT_N;
        unsigned wd = (unsigned short)f2bf(xrv) | ((unsigned)(unsigned short)f2bf(xiv) << 16);
        Xrow[m] = wd;
    }
}

// ---------------------------------------------------------------------------
// K2: MFMA block-diagonal complex MLP, in place over Xc.  (round-6 version:
// TMOD=64; per-block weight loads amortize over 64 modes — TMOD=32 regressed)
// act LDS layout: [mode m][kword d] (pitch APITCH words).
// ---------------------------------------------------------------------------
__global__ __launch_bounds__(256, 3) void mlp_mfma(const short* __restrict__ WT1,
                                                   const short* __restrict__ WT2,
                                                   const float* __restrict__ bb1,
                                                   const float* __restrict__ bb2,
                                                   unsigned int* __restrict__ Xc) {
    __shared__ __align__(16) unsigned int actA[TMOD * APITCH];  // 25.6 KB
    __shared__ __align__(16) unsigned int actB[TMOD * APITCH];  // 25.6 KB
    const int tid = threadIdx.x;
    const int chunk = blockIdx.x;          // 0..64
    const int n = blockIdx.y;
    const int b = blockIdx.z;
    const int m0 = chunk * TMOD;
    unsigned int* __restrict__ Xrow0 =
        Xc + ((size_t)b * HIDDEN + (size_t)n * BLK) * MP + m0;

    const int w = tid >> 6;                // wave 0..3
    const int l15 = tid & 15;
    const int q = (tid >> 4) & 3;
    const int outw = w * 48;
    const int mstg = tid & 63;             // staging: mode owned by this lane

    // ---- stage: 6 passes of 4 coalesced global dwords -> 1 b128 LDS write
    #pragma unroll
    for (int dp = 0; dp < 6; dp++) {
        int d0 = dp * 16 + w * 4;
        uint4 vv;
        vv.x = Xrow0[(size_t)(d0 + 0) * MP + mstg];
        vv.y = Xrow0[(size_t)(d0 + 1) * MP + mstg];
        vv.z = Xrow0[(size_t)(d0 + 2) * MP + mstg];
        vv.w = Xrow0[(size_t)(d0 + 3) * MP + mstg];
        *(uint4*)&actA[mstg * APITCH + d0] = vv;
    }

    // ---- layer-1 weight fragments (latency overlaps staging + barrier)
    short8 wf[3][6];
    for (int nl = 0; nl < 3; nl++)
        for (int ks = 0; ks < 6; ks++)
            wf[nl][ks] = *(const short8*)(WT1 + ((size_t)n * KBIG + outw + nl * 16 + l15) * KBIG + ks * 32 + q * 8);

    __syncthreads();

    // ---- layer 1 ----
    for (int mt = 0; mt < 4; mt++) {
        float4v acc[3];
        for (int nl = 0; nl < 3; nl++)
            acc[nl] = *(const float4v*)(bb1 + n * KBIG + outw + nl * 16 + q * 4);
        #pragma unroll
        for (int ks = 0; ks < 6; ks++) {
            short8 bf = *(const short8*)(&actA[(mt * 16 + l15) * APITCH + ks * 16 + q * 4]);
            acc[0] = __builtin_amdgcn_mfma_f32_16x16x32_bf16(wf[0][ks], bf, acc[0], 0, 0, 0);
            acc[1] = __builtin_amdgcn_mfma_f32_16x16x32_bf16(wf[1][ks], bf, acc[1], 0, 0, 0);
            acc[2] = __builtin_amdgcn_mfma_f32_16x16x32_bf16(wf[2][ks], bf, acc[2], 0, 0, 0);
        }
        #pragma unroll
        for (int nl = 0; nl < 3; nl++) {
            uint2 st;
            st.x = pack2bf(fmaxf(acc[nl][0], 0.f), fmaxf(acc[nl][1], 0.f));
            st.y = pack2bf(fmaxf(acc[nl][2], 0.f), fmaxf(acc[nl][3], 0.f));
            *(uint2*)&actB[(mt * 16 + l15) * APITCH + outw / 2 + nl * 8 + q * 2] = st;
        }
    }

    // ---- layer-2 weight fragments (latency overlaps barrier)
    short8 wf2[3][6];
    for (int nl = 0; nl < 3; nl++)
        for (int ks = 0; ks < 6; ks++)
            wf2[nl][ks] = *(const short8*)(WT2 + ((size_t)n * KBIG + outw + nl * 16 + l15) * KBIG + ks * 32 + q * 8);

    __syncthreads();

    // ---- layer 2 ----
    for (int mt = 0; mt < 4; mt++) {
        float4v acc[3];
        for (int nl = 0; nl < 3; nl++)
            acc[nl] = *(const float4v*)(bb2 + n * KBIG + outw + nl * 16 + q * 4);
        #pragma unroll
        for (int ks = 0; ks < 6; ks++) {
            short8 bf = *(const short8*)(&actB[(mt * 16 + l15) * APITCH + ks * 16 + q * 4]);
            acc[0] = __builtin_amdgcn_mfma_f32_16x16x32_bf16(wf2[0][ks], bf, acc[0], 0, 0, 0);
            acc[1] = __builtin_amdgcn_mfma_f32_16x16x32_bf16(wf2[1][ks], bf, acc[1], 0, 0, 0);
            acc[2] = __builtin_amdgcn_mfma_f32_16x16x32_bf16(wf2[2][ks], bf, acc[2], 0, 0, 0);
        }
        #pragma unroll
        for (int nl = 0; nl < 3; nl++) {
            float v0 = acc[nl][0], v1 = acc[nl][1], v2 = acc[nl][2], v3 = acc[nl][3];
            v0 = copysignf(fmaxf(fabsf(v0) - LAM, 0.f), v0);
            v1 = copysignf(fmaxf(fabsf(v1) - LAM, 0.f), v1);
            v2 = copysignf(fmaxf(fabsf(v2) - LAM, 0.f), v2);
            v3 = copysignf(fmaxf(fabsf(v3) - LAM, 0.f), v3);
            uint2 st;
            st.x = pack2bf(v0, v1);
            st.y = pack2bf(v2, v3);
            *(uint2*)&actA[(mt * 16 + l15) * APITCH + outw / 2 + nl * 8 + q * 2] = st;
        }
    }
    __syncthreads();

    // ---- write back: words already in global (r,i) format; b128 + coalesced
    #pragma unroll
    for (int dp = 0; dp < 6; dp++) {
        int d0 = dp * 16 + w * 4;
        uint4 vv = *(const uint4*)&actA[mstg * APITCH + d0];
        Xrow0[(size_t)(d0 + 0) * MP + mstg] = vv.x;
        Xrow0[(size_t)(d0 + 1) * MP + mstg] = vv.y;
        Xrow0[(size_t)(d0 + 2) * MP + mstg] = vv.z;
        Xrow0[(size_t)(d0 + 3) * MP + mstg] = vv.w;
    }
}

// ---------------------------------------------------------------------------
// K3: inverse rfft per (b,c): Xc -> yT [B*C, S] bf16
// ---------------------------------------------------------------------------
__global__ __launch_bounds__(256, 4) void fft_inv(const unsigned int* __restrict__ Xc,
                                                  __hip_bfloat16* __restrict__ yT,
                                                  const float2* __restrict__ tw4k,
                                                  const float2* __restrict__ tw8k) {
    __shared__ __align__(16) float2 arr[256 * 17];
    const int wg = blockIdx.x;
    const int t = threadIdx.x;
    const unsigned int* Xrow = Xc + (size_t)wg * MP;

    float2 v[16];
    #pragma unroll
    for (int j = 0; j < 16; j++) {
        int m = t + 256 * j;                       // [0,4095], coalesced
        unsigned va = Xrow[m];
        unsigned vb = Xrow[H_LEN - m];             // descending, coalesced
        float arv = bf2f((unsigned short)(va & 0xFFFF));
        float aiv = bf2f((unsigned short)(va >> 16));
        float brv = bf2f((unsigned short)(vb & 0xFFFF));
        float biv = bf2f((unsigned short)(vb >> 16));
        if (m == 0) { aiv = 0.f; biv = 0.f; }      // numpy irfft drops Im(Y0), Im(YH)
        float er = 0.5f * (arv + brv), ei = 0.5f * (aiv - biv);
        float dr = arv - brv, di = aiv + biv;
        float2 tt = tw8k[m];                       // need exp(+2*pi*i*m/8192)
        float wcs = tt.x, wsn = -tt.y;
        float or_ = 0.5f * (wcs * dr - wsn * di);
        float oi = 0.5f * (wcs * di + wsn * dr);
        v[j] = make_float2(er - oi, ei + or_);
    }

    fft3pass<true>(v, arr, tw4k, t);

    __hip_bfloat162* orow = (__hip_bfloat162*)(yT + (size_t)wg * S_LEN);
    #pragma unroll
    for (int k0 = 0; k0 < 16; k0++) {              // coalesced 4B stores
        __hip_bfloat162 w;
        w.x = __float2bfloat16(C_INV * v[k0].x);
        w.y = __float2bfloat16(C_INV * v[k0].y);
        orow[t + 256 * k0] = w;
    }
}

// ---------------------------------------------------------------------------
// K4: out[b,s,c] = x[b,s,c] + yT[b*C+c, s]. 64x64 tiles, short4 yT reads,
// float4 x read + float4 out write.
// ---------------------------------------------------------------------------
__global__ __launch_bounds__(256) void add_out(const __hip_bfloat16* __restrict__ yT,
                                               const float* __restrict__ x,
                                               float* __restrict__ out) {
    __shared__ float t[64][66];
    const int cb = blockIdx.x, sb = blockIdx.y, b = blockIdx.z;
    const int tid = threadIdx.x;
    {
        const int s4 = tid & 15, cr = tid >> 4;
        #pragma unroll
        for (int i = 0; i < 4; i++) {
            int c = cr + 16 * i;
            short4 v = *(const short4*)(yT + ((size_t)(b * HIDDEN + cb * 64 + c)) * S_LEN + sb * 64 + s4 * 4);
            t[s4 * 4 + 0][c] = bf2f((unsigned short)v.x);
            t[s4 * 4 + 1][c] = bf2f((unsigned short)v.y);
            t[s4 * 4 + 2][c] = bf2f((unsigned short)v.z);
            t[s4 * 4 + 3][c] = bf2f((unsigned short)v.w);
        }
    }
    __syncthreads();
    {
        const int cq = tid & 15, sr = tid >> 4;
        #pragma unroll
        for (int i = 0; i < 4; i++) {
            int s = sr + 16 * i;
            const size_t off = ((size_t)(b * S_LEN + sb * 64 + s)) * HIDDEN + cb * 64 + cq * 4;
            float4 xv = *(const float4*)(x + off);
            float2 a = *(const float2*)&t[s][cq * 4];
            float2 bv = *(const float2*)&t[s][cq * 4 + 2];
            float4 ov;
            ov.x = xv.x + a.x; ov.y = xv.y + a.y; ov.z = xv.z + bv.x; ov.w = xv.w + bv.y;
            *(float4*)(out + off) = ov;
        }
    }
}

// ---------------------------------------------------------------------------
extern "C" void kernel_launch(void* const* d_in, const int* in_sizes, int n_in,
                              void* d_out, int out_size, void* d_ws, size_t ws_size,
                              hipStream_t stream) {
    const float* x  = (const float*)d_in[0];
    const float* w1 = (const float*)d_in[1];
    const float* b1 = (const float*)d_in[2];
    const float* w2 = (const float*)d_in[3];
    const float* b2 = (const float*)d_in[4];
    float* out = (float*)d_out;

    char* p = (char*)d_ws;
    __hip_bfloat16* xT = (__hip_bfloat16*)p;           p += (size_t)BATCH * HIDDEN * S_LEN * 2;
    unsigned int*   Xc = (unsigned int*)p;             p += (size_t)BATCH * HIDDEN * MP * 4;
    short* WT1 = (short*)p;                            p += (size_t)NB * KBIG * KBIG * 2;
    short* WT2 = (short*)p;                            p += (size_t)NB * KBIG * KBIG * 2;
    float* bb1 = (float*)p;                            p += (size_t)NB * KBIG * 4;
    float* bb2 = (float*)p;                            p += (size_t)NB * KBIG * 4;
    float2* tw4k = (float2*)p;                         p += (size_t)4096 * sizeof(float2);
    float2* tw8k = (float2*)p;                         p += (size_t)4100 * sizeof(float2);

    prep_weights<<<(NB * KBIG * KBIG + 255) / 256, 256, 0, stream>>>(
        w1, w2, b1, b2, WT1, WT2, bb1, bb2);

    init_twiddles<<<17, 256, 0, stream>>>(tw4k, tw8k);

    transpose_in<<<dim3(HIDDEN / 64, S_LEN / 64, BATCH), 256, 0, stream>>>(x, xT);

    fft_fwd<<<BATCH * HIDDEN, 256, 0, stream>>>(xT, Xc, tw4k, tw8k);

    mlp_mfma<<<dim3(65, NB, BATCH), 256, 0, stream>>>(WT1, WT2, bb1, bb2, Xc);

    fft_inv<<<BATCH * HIDDEN, 256, 0, stream>>>(Xc, xT /* as yT */, tw4k, tw8k);

    add_out<<<dim3(HIDDEN / 64, S_LEN / 64, BATCH), 256, 0, stream>>>(xT, x, out);
}